// Round 5
// baseline (703.645 us; speedup 1.0000x reference)
//
#include <hip/hip_runtime.h>
#include <hip/hip_bf16.h>

typedef __hip_bfloat16 bf16;
typedef unsigned short u16;
typedef __attribute__((ext_vector_type(8))) short s8;   // 8 bf16 = one MFMA A/B fragment
typedef __attribute__((ext_vector_type(4))) float f4;   // MFMA C/D fragment

#define NRUNS 3
#define NTREE 128
#define TT    255
#define DD    256
#define EMB_N (10000*256)
#define PAD   258      /* LDS row stride in u16: 129 dwords -> low-conflict b32 reads */

__device__ __forceinline__ float bits2f(u16 b){ union{unsigned u; float f;} x; x.u = ((unsigned)b)<<16; return x.f; }
__device__ __forceinline__ u16   f2bits(float f){ bf16 h = __float2bfloat16(f); return *(u16*)&h; }
__device__ __forceinline__ float sigm(float x){ return 1.f/(1.f+__expf(-x)); }
__device__ __forceinline__ float tanh_(float x){ return 1.f - 2.f/(__expf(2.f*x)+1.f); }

// ---------------- dtype autodetect (round-2/4 proven) ----------------
__global__ void k_detect(const u16* __restrict__ raw, int* __restrict__ flag){
    int t = threadIdx.x;
    int hit = 0;
    if (t < 128){
        u16 w = raw[2*t];
        int e = (w >> 7) & 0xFF;
        hit = (e >= 100 && e <= 141) ? 1 : 0;
    }
    __shared__ int cnt;
    if (t == 0) cnt = 0;
    __syncthreads();
    atomicAdd(&cnt, hit);
    __syncthreads();
    if (t == 0) flag[0] = (cnt >= 64) ? 1 : 0;
}

__device__ __forceinline__ u16 cvt1b(const void* p, int i, int isb){
    return isb ? ((const u16*)p)[i] : f2bits(((const float*)p)[i]);
}
__device__ __forceinline__ float cvt1f(const void* p, int i, int isb){
    return isb ? bits2f(((const u16*)p)[i]) : ((const float*)p)[i];
}

// fused any->bf16 conversion of emb + 4 GEMM weight matrices
#define L_EMB  EMB_N
#define L_WIOU (768*256)
#define L_UIOU (768*256)
#define L_WF   (256*256)
#define L_UF   (256*256)
#define L_ALL  (L_EMB + L_WIOU + L_UIOU + L_WF + L_UF)
__global__ void k_cvtb(const void* __restrict__ s0, const void* __restrict__ s1,
                       const void* __restrict__ s2, const void* __restrict__ s3,
                       const void* __restrict__ s4,
                       u16* __restrict__ d0, u16* __restrict__ d1, u16* __restrict__ d2,
                       u16* __restrict__ d3, u16* __restrict__ d4,
                       const int* __restrict__ flag){
    int isb = flag[0];
    for (int i = blockIdx.x*blockDim.x + threadIdx.x; i < L_ALL; i += gridDim.x*blockDim.x){
        int j = i;
        if (j < L_EMB){ d0[j] = cvt1b(s0, j, isb); continue; } j -= L_EMB;
        if (j < L_WIOU){ d1[j] = cvt1b(s1, j, isb); continue; } j -= L_WIOU;
        if (j < L_UIOU){ d2[j] = cvt1b(s2, j, isb); continue; } j -= L_UIOU;
        if (j < L_WF){ d3[j] = cvt1b(s3, j, isb); continue; } j -= L_WF;
        d4[j] = cvt1b(s4, j, isb);
    }
}

// fused any->f32 conversion of biases + FC weights
#define S_BIOU 768
#define S_BF   256
#define S_F1W  (128*256)
#define S_F1B  128
#define S_F2W  (3*128)
#define S_F2B  3
#define S_ALL  (S_BIOU+S_BF+S_F1W+S_F1B+S_F2W+S_F2B)
__global__ void k_small(const void* __restrict__ s0, const void* __restrict__ s1,
                        const void* __restrict__ s2, const void* __restrict__ s3,
                        const void* __restrict__ s4, const void* __restrict__ s5,
                        float* __restrict__ d0, float* __restrict__ d1, float* __restrict__ d2,
                        float* __restrict__ d3, float* __restrict__ d4, float* __restrict__ d5,
                        const int* __restrict__ flag){
    int isb = flag[0];
    for (int i = blockIdx.x*blockDim.x + threadIdx.x; i < S_ALL; i += gridDim.x*blockDim.x){
        int j = i;
        if (j < S_BIOU){ d0[j] = cvt1f(s0, j, isb); continue; } j -= S_BIOU;
        if (j < S_BF){ d1[j] = cvt1f(s1, j, isb); continue; } j -= S_BF;
        if (j < S_F1W){ d2[j] = cvt1f(s2, j, isb); continue; } j -= S_F1W;
        if (j < S_F1B){ d3[j] = cvt1f(s3, j, isb); continue; } j -= S_F1B;
        if (j < S_F2W){ d4[j] = cvt1f(s4, j, isb); continue; } j -= S_F2W;
        d5[j] = cvt1f(s5, j, isb);
    }
}

// 16B B-fragment / direct-global A-fragment load (lane->(row ln, k=q*8+j) mapping, round-4 proven)
__device__ __forceinline__ s8 ldB16(const u16* p){
    union { uint4 q; s8 v; } u;
    u.q = *(const uint4*)p;
    return u.v;
}
// A-fragment from LDS (h transpose), 4x b32
__device__ __forceinline__ s8 ldsA(const u16* p){
    union { unsigned w[4]; s8 v; } u;
    u.w[0] = *(const unsigned*)(p);
    u.w[1] = *(const unsigned*)(p+2);
    u.w[2] = *(const unsigned*)(p+4);
    u.w[3] = *(const unsigned*)(p+6);
    return u.v;
}
#define MFMA(acc,a,b) acc = __builtin_amdgcn_mfma_f32_16x16x32_bf16(a, b, acc, 0, 0, 0)

// ---------------- fused per-level kernel ----------------
// Per block: 32 parent rows, 512 threads (8 waves). Wave w owns d-slice [w*32, w*32+32).
// GEMM-A: x.[Wiou|Wf]   (A direct from emb gather, 16B/lane)
// GEMM-B: hsum.Uiou     (A direct from contiguous hsum rows; lvl>0)
// elementwise: cs = sig(xf+hU1)*c1 + sig(xf+hU2)*c2 (2B gathers of child hU/c); cell update
// GEMM-C: h.Uf -> hU for next level (h via 16.5KB LDS transpose; lvl<7)
// hsum for next level computed IN REGISTERS (siblings are adjacent rows -> same lane).
__global__ __launch_bounds__(512, 4)
void k_tree(int lvl, int cLog,
            const int* __restrict__ f0, const int* __restrict__ f1, const int* __restrict__ f2,
            const u16* __restrict__ embb,
            const u16* __restrict__ Wiou, const u16* __restrict__ Uiou,
            const u16* __restrict__ Wfm,  const u16* __restrict__ Ufm,
            const float* __restrict__ biou_f, const float* __restrict__ bf_f,
            const u16* __restrict__ hsum_in, const u16* __restrict__ hU_in,
            const u16* __restrict__ c_in,
            u16* __restrict__ hsum_out, u16* __restrict__ hU_out,
            u16* __restrict__ c_out, u16* __restrict__ hroot)
{
    __shared__ u16 hs[32*PAD];     // 16.5 KB: h D->A transpose for GEMM-C
    const int t = threadIdx.x, w = t>>6, lane = t&63, ln = lane&15, q = lane>>4;
    const int cnt = 1 << cLog, S = 256 - 2*cnt;
    const int r0 = blockIdx.x * 32;
    const int d0 = w * 32;
    const bool haveF = (lvl > 0);
    const bool haveC = (lvl < 7);

    // per-lane A-row pointers (rows r0 + ms*16 + ln)
    const u16* ax[2];
    const u16* ah[2];
    #pragma unroll
    for (int ms = 0; ms < 2; ms++){
        int row = r0 + ms*16 + ln;
        int rb = row >> cLog, jj = row & (cnt-1);
        int run = rb >> 7, b = rb & 127;
        const int* fp = (run==0) ? f0 : ((run==1) ? f1 : f2);
        int feat = fp[b*TT + (S + jj)];
        ax[ms] = embb + (size_t)feat*DD;
        ah[ms] = hsum_in + (size_t)row*DD;
    }

    // B row-base pointers: nt 0,1=i  2,3=o  4,5=u  6,7=xf
    const u16* Bb[8];
    const u16* BbU[6];
    #pragma unroll
    for (int nt = 0; nt < 6; nt++){
        int n = (nt>>1)*256 + d0 + (nt&1)*16 + ln;
        Bb[nt]  = Wiou + (size_t)n*DD;
        BbU[nt] = Uiou + (size_t)n*DD;
    }
    Bb[6] = Wfm + (size_t)(d0 + ln)*DD;
    Bb[7] = Wfm + (size_t)(d0 + 16 + ln)*DD;

    f4 acc[8][2];
    #pragma unroll
    for (int nt = 0; nt < 8; nt++){ acc[nt][0] = (f4){0,0,0,0}; acc[nt][1] = (f4){0,0,0,0}; }

    // ---- GEMM-A: x part (K=256) ----
    #pragma unroll 2
    for (int ks = 0; ks < 8; ks++){
        int ko = ks*32 + q*8;
        s8 a0 = ldB16(ax[0] + ko);
        s8 a1 = ldB16(ax[1] + ko);
        #pragma unroll
        for (int nt = 0; nt < 6; nt++){
            s8 bb = ldB16(Bb[nt] + ko);
            MFMA(acc[nt][0], a0, bb);
            MFMA(acc[nt][1], a1, bb);
        }
        if (haveF){
            s8 b6 = ldB16(Bb[6] + ko);
            s8 b7 = ldB16(Bb[7] + ko);
            MFMA(acc[6][0], a0, b6); MFMA(acc[6][1], a1, b6);
            MFMA(acc[7][0], a0, b7); MFMA(acc[7][1], a1, b7);
        }
    }
    // ---- GEMM-B: hsum part (K=256, lvl>0) ----
    if (haveF){
        #pragma unroll 2
        for (int ks = 0; ks < 8; ks++){
            int ko = ks*32 + q*8;
            s8 a0 = ldB16(ah[0] + ko);
            s8 a1 = ldB16(ah[1] + ko);
            #pragma unroll
            for (int nt = 0; nt < 6; nt++){
                s8 bb = ldB16(BbU[nt] + ko);
                MFMA(acc[nt][0], a0, bb);
                MFMA(acc[nt][1], a1, bb);
            }
        }
    }

    // ---- epilogue: gates, cell update, hsum-in-registers, LDS h transpose ----
    #pragma unroll
    for (int nc = 0; nc < 2; nc++){
        int d = d0 + nc*16 + ln;
        float bi = biou_f[d], bo = biou_f[256+d], bu = biou_f[512+d];
        float bfv = haveF ? bf_f[d] : 0.f;
        #pragma unroll
        for (int ms = 0; ms < 2; ms++){
            float hv[4];
            #pragma unroll
            for (int r = 0; r < 4; r++){
                int row = r0 + ms*16 + q*4 + r;
                float iv = acc[0+nc][ms][r] + bi;
                float ov = acc[2+nc][ms][r] + bo;
                float uv = acc[4+nc][ms][r] + bu;
                float cs = 0.f;
                if (haveF){
                    float xf = acc[6+nc][ms][r] + bfv;
                    size_t ch = (size_t)(row*2)*DD + d;
                    float fa = sigm(xf + bits2f(hU_in[ch]));
                    float fb = sigm(xf + bits2f(hU_in[ch + DD]));
                    cs = fa*bits2f(c_in[ch]) + fb*bits2f(c_in[ch + DD]);
                }
                float c = sigm(iv)*tanh_(uv) + cs;
                float h = sigm(ov)*tanh_(c);
                hv[r] = h;
                if (haveC){
                    c_out[(size_t)row*DD + d] = f2bits(c);
                    hs[(ms*16 + q*4 + r)*PAD + d] = f2bits(h);
                } else {
                    hroot[(size_t)row*DD + d] = f2bits(h);
                }
            }
            if (haveC){   // siblings = adjacent rows, both in this lane's fragment
                int prow = (r0 + ms*16 + q*4) >> 1;
                hsum_out[(size_t)prow*DD + d]     = f2bits(hv[0] + hv[1]);
                hsum_out[(size_t)(prow+1)*DD + d] = f2bits(hv[2] + hv[3]);
            }
        }
    }

    // ---- GEMM-C: hU = h . Uf^T for the next level (lvl<7) ----
    if (haveC){
        __syncthreads();
        f4 hacc[2][2];
        #pragma unroll
        for (int nt = 0; nt < 2; nt++){ hacc[nt][0] = (f4){0,0,0,0}; hacc[nt][1] = (f4){0,0,0,0}; }
        const u16* Bf0 = Ufm + (size_t)(d0 + ln)*DD;
        const u16* Bf1 = Ufm + (size_t)(d0 + 16 + ln)*DD;
        #pragma unroll 2
        for (int ks = 0; ks < 8; ks++){
            int ko = ks*32 + q*8;
            s8 a0 = ldsA(&hs[ln*PAD + ko]);
            s8 a1 = ldsA(&hs[(16+ln)*PAD + ko]);
            s8 b0 = ldB16(Bf0 + ko);
            s8 b1 = ldB16(Bf1 + ko);
            MFMA(hacc[0][0], a0, b0); MFMA(hacc[0][1], a1, b0);
            MFMA(hacc[1][0], a0, b1); MFMA(hacc[1][1], a1, b1);
        }
        #pragma unroll
        for (int nc = 0; nc < 2; nc++){
            int d = d0 + nc*16 + ln;
            #pragma unroll
            for (int ms = 0; ms < 2; ms++)
              #pragma unroll
              for (int r = 0; r < 4; r++){
                int row = r0 + ms*16 + q*4 + r;
                hU_out[(size_t)row*DD + d] = f2bits(hacc[nc][ms][r]);
            }
        }
    }
}

// ---------------- final: bilinear combine + MLP (round-2/4 proven epilogue) ----------------
__global__ __launch_bounds__(256)
void k_final(const u16* __restrict__ hroot,
             const float* __restrict__ fc1w, const float* __restrict__ fc1b,
             const float* __restrict__ fc2w, const float* __restrict__ fc2b,
             void* __restrict__ out, const int* __restrict__ flag)
{
    int b = blockIdx.x, t = threadIdx.x;
    __shared__ float sprod[DD];
    __shared__ float shb[DD];
    __shared__ float shid[128];
    float hc  = bits2f(hroot[(0*NTREE + b)*DD + t]);
    float ha  = bits2f(hroot[(1*NTREE + b)*DD + t]);
    float hbv = bits2f(hroot[(2*NTREE + b)*DD + t]);
    sprod[t] = hc * ha;
    shb[t]   = hbv;
    __syncthreads();
    for (int s = 128; s > 0; s >>= 1){
        if (t < s) sprod[t] += sprod[t + s];
        __syncthreads();
    }
    float dot = sprod[0];
    if (t < 128){
        float acc = fc1b[t];
        for (int k = 0; k < DD; k++)
            acc = fmaf(dot * shb[k], fc1w[t*DD + k], acc);
        shid[t] = fmaxf(acc, 0.f);
    }
    __syncthreads();
    if (t < 3){
        float acc = fc2b[t];
        for (int j = 0; j < 128; j++)
            acc = fmaf(fc2w[t*128 + j], shid[j], acc);
        float v = fmaxf(acc, 0.f);
        if (flag[0]) ((bf16*)out)[b*3 + t] = __float2bfloat16(v);
        else         ((float*)out)[b*3 + t] = v;
    }
}

extern "C" void kernel_launch(void* const* d_in, const int* in_sizes, int n_in,
                              void* d_out, int out_size, void* d_ws, size_t ws_size,
                              hipStream_t stream)
{
    const int* f0 = (const int*)d_in[0];
    const int* f1 = (const int*)d_in[1];
    const int* f2 = (const int*)d_in[2];
    // d_in[3..7] static forest metadata — unused (structure compile-time known)
    const void* emb  = d_in[8];
    const void* Wiou = d_in[9];
    const void* biou = d_in[10];
    const void* Uiou = d_in[11];
    const void* Wf   = d_in[12];
    const void* bfv  = d_in[13];
    const void* Uf   = d_in[14];
    const void* fc1w = d_in[15];
    const void* fc1b = d_in[16];
    const void* fc2w = d_in[17];
    const void* fc2b = d_in[18];

    char* base = (char*)d_ws;
    size_t off = 0;
    auto take = [&](size_t bytes) -> char* {
        char* p = base + off;
        off = (off + bytes + 255) & ~(size_t)255;
        return p;
    };
    int*   flag   = (int*)  take(256);
    u16*   embb   = (u16*)  take((size_t)L_EMB*2);
    u16*   wioub  = (u16*)  take((size_t)L_WIOU*2);
    u16*   uioub  = (u16*)  take((size_t)L_UIOU*2);
    u16*   wfb    = (u16*)  take((size_t)L_WF*2);
    u16*   ufb    = (u16*)  take((size_t)L_UF*2);
    float* biou_f = (float*)take(S_BIOU*4);
    float* bf_f   = (float*)take(S_BF*4);
    float* fc1w_f = (float*)take(S_F1W*4);
    float* fc1b_f = (float*)take(S_F1B*4);
    float* fc2w_f = (float*)take(S_F2W*4);
    float* fc2b_f = (float*)take(S_F2B*4);
    // ping-pong buffers by level parity (even levels -> slot 0)
    u16* U0 = (u16*)take((size_t)49152*DD*2);   // hU, even lvl  (25.2 MB)
    u16* U1 = (u16*)take((size_t)24576*DD*2);   // hU, odd lvl   (12.6 MB)
    u16* C0 = (u16*)take((size_t)49152*DD*2);   // c,  even lvl
    u16* C1 = (u16*)take((size_t)24576*DD*2);   // c,  odd lvl
    u16* HA = (u16*)take((size_t)24576*DD*2);   // hsum written at even lvl
    u16* HB = (u16*)take((size_t)12288*DD*2);   // hsum written at odd lvl
    u16* hroot = (u16*)take((size_t)NRUNS*NTREE*DD*2);
    // total ~101 MB (< proven 119 MB)

    k_detect<<<1, 256, 0, stream>>>((const u16*)emb, flag);
    k_cvtb<<<2048, 256, 0, stream>>>(emb, Wiou, Uiou, Wf, Uf,
                                     embb, wioub, uioub, wfb, ufb, flag);
    k_small<<<135, 256, 0, stream>>>(biou, bfv, fc1w, fc1b, fc2w, fc2b,
                                     biou_f, bf_f, fc1w_f, fc1b_f, fc2w_f, fc2b_f, flag);

    for (int lvl = 0; lvl <= 7; lvl++){
        int cLog = 7 - lvl;
        int rows = NRUNS*NTREE*(128 >> lvl);
        int blocks = rows / 32;
        int pe = lvl & 1;          // this level's parity
        u16* hU_o   = pe ? U1 : U0;
        u16* c_o    = pe ? C1 : C0;
        u16* hsum_o = pe ? HB : HA;
        const u16* hU_i   = pe ? U0 : U1;   // children = opposite parity
        const u16* c_i    = pe ? C0 : C1;
        const u16* hsum_i = pe ? HA : HB;   // hsum for THIS level written by child level
        k_tree<<<blocks, 512, 0, stream>>>(lvl, cLog, f0, f1, f2, embb,
                                           wioub, uioub, wfb, ufb,
                                           biou_f, bf_f,
                                           hsum_i, hU_i, c_i,
                                           hsum_o, hU_o, c_o, hroot);
    }
    k_final<<<NTREE, 256, 0, stream>>>(hroot, fc1w_f, fc1b_f, fc2w_f, fc2b_f, d_out, flag);
}

// Round 6
// 489.168 us; speedup vs baseline: 1.4385x; 1.4385x over previous
//
#include <hip/hip_runtime.h>
#include <hip/hip_bf16.h>

typedef __hip_bfloat16 bf16;
typedef unsigned short u16;
typedef __attribute__((ext_vector_type(8))) short s8;   // 8 bf16 = one MFMA A/B fragment
typedef __attribute__((ext_vector_type(4))) float f4;   // MFMA C/D fragment

#define NRUNS 3
#define NTREE 128
#define TT    255
#define DD    256
#define VPAD  10016    /* vocab padded to 32 */
#define PAD   258      /* LDS row stride in u16 */

__device__ __forceinline__ float bits2f(u16 b){ union{unsigned u; float f;} x; x.u = ((unsigned)b)<<16; return x.f; }
__device__ __forceinline__ u16   f2bits(float f){ bf16 h = __float2bfloat16(f); return *(u16*)&h; }
__device__ __forceinline__ float sigm(float x){ return 1.f/(1.f+__expf(-x)); }
__device__ __forceinline__ float tanh_(float x){ return 1.f - 2.f/(__expf(2.f*x)+1.f); }

// ---------------- dtype autodetect (round-2/4/5 proven) ----------------
__global__ void k_detect(const u16* __restrict__ raw, int* __restrict__ flag){
    int t = threadIdx.x;
    int hit = 0;
    if (t < 128){
        u16 w = raw[2*t];
        int e = (w >> 7) & 0xFF;
        hit = (e >= 100 && e <= 141) ? 1 : 0;
    }
    __shared__ int cnt;
    if (t == 0) cnt = 0;
    __syncthreads();
    atomicAdd(&cnt, hit);
    __syncthreads();
    if (t == 0) flag[0] = (cnt >= 64) ? 1 : 0;
}

__device__ __forceinline__ u16 cvt1b(const void* p, int i, int isb){
    return isb ? ((const u16*)p)[i] : f2bits(((const float*)p)[i]);
}
__device__ __forceinline__ float cvt1f(const void* p, int i, int isb){
    return isb ? bits2f(((const u16*)p)[i]) : ((const float*)p)[i];
}

// fused any->bf16 conversion: emb (zero-padded to VPAD rows) + 4 weights
#define L_EMB  (10000*256)
#define L_EMBP (VPAD*256)
#define L_WIOU (768*256)
#define L_UIOU (768*256)
#define L_WF   (256*256)
#define L_UF   (256*256)
#define L_ALL  (L_EMBP + L_WIOU + L_UIOU + L_WF + L_UF)
__global__ void k_cvtb(const void* __restrict__ s0, const void* __restrict__ s1,
                       const void* __restrict__ s2, const void* __restrict__ s3,
                       const void* __restrict__ s4,
                       u16* __restrict__ d0, u16* __restrict__ d1, u16* __restrict__ d2,
                       u16* __restrict__ d3, u16* __restrict__ d4,
                       const int* __restrict__ flag){
    int isb = flag[0];
    for (int i = blockIdx.x*blockDim.x + threadIdx.x; i < L_ALL; i += gridDim.x*blockDim.x){
        int j = i;
        if (j < L_EMBP){ d0[j] = (j < L_EMB) ? cvt1b(s0, j, isb) : (u16)0; continue; } j -= L_EMBP;
        if (j < L_WIOU){ d1[j] = cvt1b(s1, j, isb); continue; } j -= L_WIOU;
        if (j < L_UIOU){ d2[j] = cvt1b(s2, j, isb); continue; } j -= L_UIOU;
        if (j < L_WF){ d3[j] = cvt1b(s3, j, isb); continue; } j -= L_WF;
        d4[j] = cvt1b(s4, j, isb);
    }
}

// fused any->f32 conversion of biases + FC weights
#define S_BIOU 768
#define S_BF   256
#define S_F1W  (128*256)
#define S_F1B  128
#define S_F2W  (3*128)
#define S_F2B  3
#define S_ALL  (S_BIOU+S_BF+S_F1W+S_F1B+S_F2W+S_F2B)
__global__ void k_small(const void* __restrict__ s0, const void* __restrict__ s1,
                        const void* __restrict__ s2, const void* __restrict__ s3,
                        const void* __restrict__ s4, const void* __restrict__ s5,
                        float* __restrict__ d0, float* __restrict__ d1, float* __restrict__ d2,
                        float* __restrict__ d3, float* __restrict__ d4, float* __restrict__ d5,
                        const int* __restrict__ flag){
    int isb = flag[0];
    for (int i = blockIdx.x*blockDim.x + threadIdx.x; i < S_ALL; i += gridDim.x*blockDim.x){
        int j = i;
        if (j < S_BIOU){ d0[j] = cvt1f(s0, j, isb); continue; } j -= S_BIOU;
        if (j < S_BF){ d1[j] = cvt1f(s1, j, isb); continue; } j -= S_BF;
        if (j < S_F1W){ d2[j] = cvt1f(s2, j, isb); continue; } j -= S_F1W;
        if (j < S_F1B){ d3[j] = cvt1f(s3, j, isb); continue; } j -= S_F1B;
        if (j < S_F2W){ d4[j] = cvt1f(s4, j, isb); continue; } j -= S_F2W;
        d5[j] = cvt1f(s5, j, isb);
    }
}

__device__ __forceinline__ s8 ldB16(const u16* p){
    union { uint4 q; s8 v; } u;
    u.q = *(const uint4*)p;
    return u.v;
}
__device__ __forceinline__ s8 ldsA(const u16* p){
    union { unsigned w[4]; s8 v; } u;
    u.w[0] = *(const unsigned*)(p);
    u.w[1] = *(const unsigned*)(p+2);
    u.w[2] = *(const unsigned*)(p+4);
    u.w[3] = *(const unsigned*)(p+6);
    return u.v;
}
#define MFMA(acc,a,b) acc = __builtin_amdgcn_mfma_f32_16x16x32_bf16(a, b, acc, 0, 0, 0)

// ---------------- vocab projection: E_iou = emb@Wiou^T, E_f = emb@Wf^T ----------------
// 32 vocab rows/block, 512 thr; wave w owns n-slice [w*128, w*128+128) of 1024 (=768 iou | 256 f)
__global__ __launch_bounds__(512, 4)
void k_vocab(const u16* __restrict__ embb,
             const u16* __restrict__ Wiou, const u16* __restrict__ Wfm,
             u16* __restrict__ E_iou, u16* __restrict__ E_f)
{
    const int t = threadIdx.x, w = t>>6, lane = t&63, ln = lane&15, q = lane>>4;
    const int r0 = blockIdx.x*32, n0 = w*128;

    const u16* Bp[8];
    #pragma unroll
    for (int nt = 0; nt < 8; nt++){
        int n = n0 + nt*16 + ln;
        Bp[nt] = (n < 768) ? (Wiou + (size_t)n*DD) : (Wfm + (size_t)(n-768)*DD);
    }
    const u16* a0p = embb + (size_t)(r0+ln)*DD;
    const u16* a1p = embb + (size_t)(r0+16+ln)*DD;

    f4 acc[8][2];
    #pragma unroll
    for (int nt = 0; nt < 8; nt++){ acc[nt][0] = (f4){0,0,0,0}; acc[nt][1] = (f4){0,0,0,0}; }

    #pragma unroll 2
    for (int ks = 0; ks < 8; ks++){
        int ko = ks*32 + q*8;
        s8 a0 = ldB16(a0p + ko);
        s8 a1 = ldB16(a1p + ko);
        #pragma unroll
        for (int nt = 0; nt < 8; nt++){
            s8 bb = ldB16(Bp[nt] + ko);
            MFMA(acc[nt][0], a0, bb);
            MFMA(acc[nt][1], a1, bb);
        }
    }
    #pragma unroll
    for (int nt = 0; nt < 8; nt++){
        int n = n0 + nt*16 + ln;
        #pragma unroll
        for (int ms = 0; ms < 2; ms++)
          #pragma unroll
          for (int r = 0; r < 4; r++){
            int v = r0 + ms*16 + q*4 + r;
            u16 val = f2bits(acc[nt][ms][r]);
            if (n < 768) E_iou[(size_t)v*768 + n] = val;
            else         E_f[(size_t)v*DD + (n-768)] = val;
        }
    }
}

// ---------------- per-level kernel ----------------
// Level L: rows = 3*128*(128>>L) nodes. 32 rows/block, 512 thr; wave owns d-slice w*32..+32.
// iou = E_iou[feat] + hsum_in@Uiou^T + b ; c = sig(i)tanh(u) + fcsum_in ; h = sig(o)tanh(c)
// then (L<7): hU = h@Uf^T (LDS transpose); fc = sig(E_f[feat_parent]+b_f+hU)*c;
// hsum_out / fcsum_out pair-reduced IN REGISTERS (siblings adjacent rows, same lane).
__global__ __launch_bounds__(512, 4)
void k_lvl(int lvl, int cLog,
           const int* __restrict__ f0, const int* __restrict__ f1, const int* __restrict__ f2,
           const u16* __restrict__ E_iou, const u16* __restrict__ E_f,
           const u16* __restrict__ Uiou, const u16* __restrict__ Ufm,
           const float* __restrict__ biou_f, const float* __restrict__ bf_f,
           const u16* __restrict__ hsum_in, const u16* __restrict__ fcsum_in,
           u16* __restrict__ hsum_out, u16* __restrict__ fcsum_out,
           u16* __restrict__ hroot)
{
    __shared__ u16 hs[32*PAD];   // 16.5 KB: h D->A transpose for the hU GEMM
    const int t = threadIdx.x, w = t>>6, lane = t&63, ln = lane&15, q = lane>>4;
    const int cnt = 1 << cLog, S = 256 - 2*cnt;
    const int r0 = blockIdx.x*32, d0 = w*32;
    const bool haveU = (lvl > 0);
    const bool haveP = (lvl < 7);

    // decode feats for own rows + parents
    int feat[2][4], featp[2][2];
    #pragma unroll
    for (int ms = 0; ms < 2; ms++)
      #pragma unroll
      for (int r = 0; r < 4; r++){
        int rho = r0 + ms*16 + q*4 + r;
        int run = rho >> (7+cLog);
        int rem = rho & ((1<<(7+cLog)) - 1);
        int b = rem >> cLog, jj = rem & (cnt-1);
        const int* fp = (run==0) ? f0 : ((run==1) ? f1 : f2);
        feat[ms][r] = fp[b*TT + S + jj];
        if (haveP && (r&1)==0)
            featp[ms][r>>1] = fp[b*TT + (256-cnt) + (jj>>1)];
      }

    // ---- GEMM-U: hsum_in @ Uiou^T (6 n-tiles: nt = 2*g + nc) ----
    f4 acc[6][2];
    #pragma unroll
    for (int nt = 0; nt < 6; nt++){ acc[nt][0] = (f4){0,0,0,0}; acc[nt][1] = (f4){0,0,0,0}; }
    if (haveU){
        const u16* a0p = hsum_in + (size_t)(r0+ln)*DD;
        const u16* a1p = hsum_in + (size_t)(r0+16+ln)*DD;
        const u16* Bp[6];
        #pragma unroll
        for (int nt = 0; nt < 6; nt++){
            int n = (nt>>1)*256 + d0 + (nt&1)*16 + ln;
            Bp[nt] = Uiou + (size_t)n*DD;
        }
        #pragma unroll 2
        for (int ks = 0; ks < 8; ks++){
            int ko = ks*32 + q*8;
            s8 a0 = ldB16(a0p + ko);
            s8 a1 = ldB16(a1p + ko);
            #pragma unroll
            for (int nt = 0; nt < 6; nt++){
                s8 bb = ldB16(Bp[nt] + ko);
                MFMA(acc[nt][0], a0, bb);
                MFMA(acc[nt][1], a1, bb);
            }
        }
    }

    // ---- epilogue: cell update; hsum pair-reduce in registers ----
    float cv[2][2][4];
    #pragma unroll
    for (int nc = 0; nc < 2; nc++){
        int d = d0 + nc*16 + ln;
        float bi = biou_f[d], bo = biou_f[256+d], bu = biou_f[512+d];
        #pragma unroll
        for (int ms = 0; ms < 2; ms++){
            float hv[4];
            #pragma unroll
            for (int r = 0; r < 4; r++){
                int rho = r0 + ms*16 + q*4 + r;
                size_t eb = (size_t)feat[ms][r]*768 + d;
                float iv = acc[0+nc][ms][r] + bits2f(E_iou[eb])       + bi;
                float ov = acc[2+nc][ms][r] + bits2f(E_iou[eb + 256]) + bo;
                float uv = acc[4+nc][ms][r] + bits2f(E_iou[eb + 512]) + bu;
                float cs = haveU ? bits2f(fcsum_in[(size_t)rho*DD + d]) : 0.f;
                float c = sigm(iv)*tanh_(uv) + cs;
                float h = sigm(ov)*tanh_(c);
                cv[nc][ms][r] = c;
                hv[r] = h;
                if (haveP) hs[(ms*16 + q*4 + r)*PAD + d] = f2bits(h);
                else       hroot[(size_t)rho*DD + d] = f2bits(h);
            }
            if (haveP){
                int prow = (r0>>1) + ms*8 + q*2;
                hsum_out[(size_t)prow*DD + d]     = f2bits(hv[0] + hv[1]);
                hsum_out[(size_t)(prow+1)*DD + d] = f2bits(hv[2] + hv[3]);
            }
        }
    }

    // ---- GEMM-C: hU = h@Uf^T, then fc = sig(E_f[parent]+bf+hU)*c, pair-reduce ----
    if (haveP){
        __syncthreads();
        f4 hacc[2][2];
        #pragma unroll
        for (int nt = 0; nt < 2; nt++){ hacc[nt][0] = (f4){0,0,0,0}; hacc[nt][1] = (f4){0,0,0,0}; }
        const u16* Bf0 = Ufm + (size_t)(d0 + ln)*DD;
        const u16* Bf1 = Ufm + (size_t)(d0 + 16 + ln)*DD;
        #pragma unroll 2
        for (int ks = 0; ks < 8; ks++){
            int ko = ks*32 + q*8;
            s8 a0 = ldsA(&hs[ln*PAD + ko]);
            s8 a1 = ldsA(&hs[(16+ln)*PAD + ko]);
            s8 b0 = ldB16(Bf0 + ko);
            s8 b1 = ldB16(Bf1 + ko);
            MFMA(hacc[0][0], a0, b0); MFMA(hacc[0][1], a1, b0);
            MFMA(hacc[1][0], a0, b1); MFMA(hacc[1][1], a1, b1);
        }
        #pragma unroll
        for (int nc = 0; nc < 2; nc++){
            int d = d0 + nc*16 + ln;
            float bfv = bf_f[d];
            #pragma unroll
            for (int ms = 0; ms < 2; ms++){
                float fs0, fs1;
                #pragma unroll
                for (int r = 0; r < 4; r++){
                    float ef = bits2f(E_f[(size_t)featp[ms][r>>1]*DD + d]);
                    float fc = sigm(ef + bfv + hacc[nc][ms][r]) * cv[nc][ms][r];
                    if (r == 0) fs0 = fc;
                    else if (r == 1) fs0 += fc;
                    else if (r == 2) fs1 = fc;
                    else fs1 += fc;
                }
                int prow = (r0>>1) + ms*8 + q*2;
                fcsum_out[(size_t)prow*DD + d]     = f2bits(fs0);
                fcsum_out[(size_t)(prow+1)*DD + d] = f2bits(fs1);
            }
        }
    }
}

// ---------------- final: bilinear combine + MLP (proven epilogue) ----------------
__global__ __launch_bounds__(256)
void k_final(const u16* __restrict__ hroot,
             const float* __restrict__ fc1w, const float* __restrict__ fc1b,
             const float* __restrict__ fc2w, const float* __restrict__ fc2b,
             void* __restrict__ out, const int* __restrict__ flag)
{
    int b = blockIdx.x, t = threadIdx.x;
    __shared__ float sprod[DD];
    __shared__ float shb[DD];
    __shared__ float shid[128];
    float hc  = bits2f(hroot[(0*NTREE + b)*DD + t]);
    float ha  = bits2f(hroot[(1*NTREE + b)*DD + t]);
    float hbv = bits2f(hroot[(2*NTREE + b)*DD + t]);
    sprod[t] = hc * ha;
    shb[t]   = hbv;
    __syncthreads();
    for (int s = 128; s > 0; s >>= 1){
        if (t < s) sprod[t] += sprod[t + s];
        __syncthreads();
    }
    float dot = sprod[0];
    if (t < 128){
        float acc = fc1b[t];
        for (int k = 0; k < DD; k++)
            acc = fmaf(dot * shb[k], fc1w[t*DD + k], acc);
        shid[t] = fmaxf(acc, 0.f);
    }
    __syncthreads();
    if (t < 3){
        float acc = fc2b[t];
        for (int j = 0; j < 128; j++)
            acc = fmaf(fc2w[t*128 + j], shid[j], acc);
        float v = fmaxf(acc, 0.f);
        if (flag[0]) ((bf16*)out)[b*3 + t] = __float2bfloat16(v);
        else         ((float*)out)[b*3 + t] = v;
    }
}

extern "C" void kernel_launch(void* const* d_in, const int* in_sizes, int n_in,
                              void* d_out, int out_size, void* d_ws, size_t ws_size,
                              hipStream_t stream)
{
    const int* f0 = (const int*)d_in[0];
    const int* f1 = (const int*)d_in[1];
    const int* f2 = (const int*)d_in[2];
    // d_in[3..7] static forest metadata — unused (structure compile-time known)
    const void* emb  = d_in[8];
    const void* Wiou = d_in[9];
    const void* biou = d_in[10];
    const void* Uiou = d_in[11];
    const void* Wf   = d_in[12];
    const void* bfv  = d_in[13];
    const void* Uf   = d_in[14];
    const void* fc1w = d_in[15];
    const void* fc1b = d_in[16];
    const void* fc2w = d_in[17];
    const void* fc2b = d_in[18];

    char* base = (char*)d_ws;
    size_t off = 0;
    auto take = [&](size_t bytes) -> char* {
        char* p = base + off;
        off = (off + bytes + 255) & ~(size_t)255;
        return p;
    };
    int*   flag   = (int*)  take(256);
    u16*   embb   = (u16*)  take((size_t)L_EMBP*2);        // 5.13 MB (padded)
    u16*   wioub  = (u16*)  take((size_t)L_WIOU*2);
    u16*   uioub  = (u16*)  take((size_t)L_UIOU*2);
    u16*   wfb    = (u16*)  take((size_t)L_WF*2);
    u16*   ufb    = (u16*)  take((size_t)L_UF*2);
    float* biou_f = (float*)take(S_BIOU*4);
    float* bf_f   = (float*)take(S_BF*4);
    float* fc1w_f = (float*)take(S_F1W*4);
    float* fc1b_f = (float*)take(S_F1B*4);
    float* fc2w_f = (float*)take(S_F2W*4);
    float* fc2b_f = (float*)take(S_F2B*4);
    u16*   E_iou  = (u16*)  take((size_t)VPAD*768*2);      // 15.4 MB
    u16*   E_f    = (u16*)  take((size_t)VPAD*256*2);      // 5.13 MB
    u16*   HA     = (u16*)  take((size_t)24576*DD*2);      // hsum from even lvls (12.6 MB)
    u16*   HB     = (u16*)  take((size_t)12288*DD*2);      // hsum from odd lvls (6.3 MB)
    u16*   FA     = (u16*)  take((size_t)24576*DD*2);      // fcsum from even lvls
    u16*   FB     = (u16*)  take((size_t)12288*DD*2);      // fcsum from odd lvls
    u16*   hroot  = (u16*)  take((size_t)NRUNS*NTREE*DD*2);
    // total ~65 MB (< proven 119 MB)

    k_detect<<<1, 256, 0, stream>>>((const u16*)emb, flag);
    k_cvtb<<<2048, 256, 0, stream>>>(emb, Wiou, Uiou, Wf, Uf,
                                     embb, wioub, uioub, wfb, ufb, flag);
    k_small<<<135, 256, 0, stream>>>(biou, bfv, fc1w, fc1b, fc2w, fc2b,
                                     biou_f, bf_f, fc1w_f, fc1b_f, fc2w_f, fc2b_f, flag);
    k_vocab<<<VPAD/32, 512, 0, stream>>>(embb, wioub, wfb, E_iou, E_f);

    for (int lvl = 0; lvl <= 7; lvl++){
        int cLog = 7 - lvl;
        int rows = NRUNS*NTREE*(128 >> lvl);
        int blocks = rows / 32;
        int pe = lvl & 1;
        u16* hs_o = pe ? HB : HA;            // this level writes its parity slot
        u16* fc_o = pe ? FB : FA;
        const u16* hs_i = pe ? HA : HB;      // reads child level's slot (opposite parity)
        const u16* fc_i = pe ? FA : FB;
        k_lvl<<<blocks, 512, 0, stream>>>(lvl, cLog, f0, f1, f2,
                                          E_iou, E_f, uioub, ufb,
                                          biou_f, bf_f,
                                          hs_i, fc_i, hs_o, fc_o, hroot);
    }
    k_final<<<NTREE, 256, 0, stream>>>(hroot, fc1w_f, fc1b_f, fc2w_f, fc2b_f, d_out, flag);
}

// Round 7
// 465.331 us; speedup vs baseline: 1.5121x; 1.0512x over previous
//
#include <hip/hip_runtime.h>
#include <hip/hip_bf16.h>

typedef __hip_bfloat16 bf16;
typedef unsigned short u16;
typedef __attribute__((ext_vector_type(8))) short s8;   // 8 bf16 = one MFMA A/B fragment
typedef __attribute__((ext_vector_type(4))) float f4;   // MFMA C/D fragment

#define NRUNS 3
#define NTREE 128
#define TT    255
#define DD    256
#define VPAD  10016    /* vocab padded to 32 */
#define PAD   258      /* LDS row stride in u16 */
#define ESTR  1026     /* LDS stride for 1024-wide E staging rows */

__device__ __forceinline__ float bits2f(u16 b){ union{unsigned u; float f;} x; x.u = ((unsigned)b)<<16; return x.f; }
__device__ __forceinline__ u16   f2bits(float f){ bf16 h = __float2bfloat16(f); return *(u16*)&h; }
__device__ __forceinline__ float sigm(float x){ return 1.f/(1.f+__expf(-x)); }
__device__ __forceinline__ float tanh_(float x){ return 1.f - 2.f/(__expf(2.f*x)+1.f); }

// ---------------- dtype autodetect (proven) ----------------
__global__ void k_detect(const u16* __restrict__ raw, int* __restrict__ flag){
    int t = threadIdx.x;
    int hit = 0;
    if (t < 128){
        u16 w = raw[2*t];
        int e = (w >> 7) & 0xFF;
        hit = (e >= 100 && e <= 141) ? 1 : 0;
    }
    __shared__ int cnt;
    if (t == 0) cnt = 0;
    __syncthreads();
    atomicAdd(&cnt, hit);
    __syncthreads();
    if (t == 0) flag[0] = (cnt >= 64) ? 1 : 0;
}

__device__ __forceinline__ u16 cvt1b(const void* p, int i, int isb){
    return isb ? ((const u16*)p)[i] : f2bits(((const float*)p)[i]);
}
__device__ __forceinline__ float cvt1f(const void* p, int i, int isb){
    return isb ? bits2f(((const u16*)p)[i]) : ((const float*)p)[i];
}

// fused any->bf16 conversion: emb (zero-padded to VPAD rows) + 4 weights
#define L_EMB  (10000*256)
#define L_EMBP (VPAD*256)
#define L_WIOU (768*256)
#define L_UIOU (768*256)
#define L_WF   (256*256)
#define L_UF   (256*256)
#define L_ALL  (L_EMBP + L_WIOU + L_UIOU + L_WF + L_UF)
__global__ void k_cvtb(const void* __restrict__ s0, const void* __restrict__ s1,
                       const void* __restrict__ s2, const void* __restrict__ s3,
                       const void* __restrict__ s4,
                       u16* __restrict__ d0, u16* __restrict__ d1, u16* __restrict__ d2,
                       u16* __restrict__ d3, u16* __restrict__ d4,
                       const int* __restrict__ flag){
    int isb = flag[0];
    for (int i = blockIdx.x*blockDim.x + threadIdx.x; i < L_ALL; i += gridDim.x*blockDim.x){
        int j = i;
        if (j < L_EMBP){ d0[j] = (j < L_EMB) ? cvt1b(s0, j, isb) : (u16)0; continue; } j -= L_EMBP;
        if (j < L_WIOU){ d1[j] = cvt1b(s1, j, isb); continue; } j -= L_WIOU;
        if (j < L_UIOU){ d2[j] = cvt1b(s2, j, isb); continue; } j -= L_UIOU;
        if (j < L_WF){ d3[j] = cvt1b(s3, j, isb); continue; } j -= L_WF;
        d4[j] = cvt1b(s4, j, isb);
    }
}

// fused any->f32 conversion of biases + FC weights
#define S_BIOU 768
#define S_BF   256
#define S_F1W  (128*256)
#define S_F1B  128
#define S_F2W  (3*128)
#define S_F2B  3
#define S_ALL  (S_BIOU+S_BF+S_F1W+S_F1B+S_F2W+S_F2B)
__global__ void k_small(const void* __restrict__ s0, const void* __restrict__ s1,
                        const void* __restrict__ s2, const void* __restrict__ s3,
                        const void* __restrict__ s4, const void* __restrict__ s5,
                        float* __restrict__ d0, float* __restrict__ d1, float* __restrict__ d2,
                        float* __restrict__ d3, float* __restrict__ d4, float* __restrict__ d5,
                        const int* __restrict__ flag){
    int isb = flag[0];
    for (int i = blockIdx.x*blockDim.x + threadIdx.x; i < S_ALL; i += gridDim.x*blockDim.x){
        int j = i;
        if (j < S_BIOU){ d0[j] = cvt1f(s0, j, isb); continue; } j -= S_BIOU;
        if (j < S_BF){ d1[j] = cvt1f(s1, j, isb); continue; } j -= S_BF;
        if (j < S_F1W){ d2[j] = cvt1f(s2, j, isb); continue; } j -= S_F1W;
        if (j < S_F1B){ d3[j] = cvt1f(s3, j, isb); continue; } j -= S_F1B;
        if (j < S_F2W){ d4[j] = cvt1f(s4, j, isb); continue; } j -= S_F2W;
        d5[j] = cvt1f(s5, j, isb);
    }
}

__device__ __forceinline__ s8 ldB16(const u16* p){
    union { uint4 q; s8 v; } u;
    u.q = *(const uint4*)p;
    return u.v;
}
__device__ __forceinline__ s8 ldsA(const u16* p){
    union { unsigned w[4]; s8 v; } u;
    u.w[0] = *(const unsigned*)(p);
    u.w[1] = *(const unsigned*)(p+2);
    u.w[2] = *(const unsigned*)(p+4);
    u.w[3] = *(const unsigned*)(p+6);
    return u.v;
}
#define MFMA(acc,a,b) acc = __builtin_amdgcn_mfma_f32_16x16x32_bf16(a, b, acc, 0, 0, 0)

// ---------------- vocab-space precompute ----------------
// E_iou = emb@Wiou^T (raw, pre-bias), E_f = emb@Wf^T (raw),
// H0/C0 = leaf h/c per vocab entry, HU0 = H0@Uf^T.
__global__ __launch_bounds__(512, 2)
void k_vocab2(const u16* __restrict__ embb,
              const u16* __restrict__ Wiou, const u16* __restrict__ Wfm,
              const u16* __restrict__ Ufm,  const float* __restrict__ biou_f,
              u16* __restrict__ E_iou, u16* __restrict__ E_f,
              u16* __restrict__ H0, u16* __restrict__ C0, u16* __restrict__ HU0)
{
    __shared__ u16 es[32*ESTR];   // 65.7 KB: full 1024-wide iou|f staging
    __shared__ u16 hs[32*PAD];    // 16.5 KB: h0 for the HU0 GEMM
    const int t = threadIdx.x, w = t>>6, lane = t&63, ln = lane&15, q = lane>>4;
    const int r0 = blockIdx.x*32, n0 = w*128;

    // ---- GEMM: emb @ [Wiou|Wf]^T (round-6 proven pattern) ----
    const u16* Bp[8];
    #pragma unroll
    for (int nt = 0; nt < 8; nt++){
        int n = n0 + nt*16 + ln;
        Bp[nt] = (n < 768) ? (Wiou + (size_t)n*DD) : (Wfm + (size_t)(n-768)*DD);
    }
    const u16* a0p = embb + (size_t)(r0+ln)*DD;
    const u16* a1p = embb + (size_t)(r0+16+ln)*DD;
    f4 acc[8][2];
    #pragma unroll
    for (int nt = 0; nt < 8; nt++){ acc[nt][0] = (f4){0,0,0,0}; acc[nt][1] = (f4){0,0,0,0}; }
    #pragma unroll 2
    for (int ks = 0; ks < 8; ks++){
        int ko = ks*32 + q*8;
        s8 a0 = ldB16(a0p + ko);
        s8 a1 = ldB16(a1p + ko);
        #pragma unroll
        for (int nt = 0; nt < 8; nt++){
            s8 bb = ldB16(Bp[nt] + ko);
            MFMA(acc[nt][0], a0, bb);
            MFMA(acc[nt][1], a1, bb);
        }
    }
    // stage D into LDS (full 32x1024)
    #pragma unroll
    for (int nt = 0; nt < 8; nt++){
        int n = n0 + nt*16 + ln;
        #pragma unroll
        for (int ms = 0; ms < 2; ms++)
          #pragma unroll
          for (int r = 0; r < 4; r++)
            es[(ms*16 + q*4 + r)*ESTR + n] = f2bits(acc[nt][ms][r]);
    }
    __syncthreads();

    // ---- phase 2a: copy E to global (16B chunks) ----
    for (int it = 0; it < 8; it++){
        int idx = it*512 + t;            // 0..4095
        int row = idx >> 7, c = idx & 127;
        int n = c*8;
        union { unsigned w4[4]; uint4 q4; } u;
        const u16* p = &es[row*ESTR + n];
        u.w4[0] = *(const unsigned*)(p);
        u.w4[1] = *(const unsigned*)(p+2);
        u.w4[2] = *(const unsigned*)(p+4);
        u.w4[3] = *(const unsigned*)(p+6);
        int vrow = r0 + row;
        if (n < 768) *(uint4*)(E_iou + (size_t)vrow*768 + n) = u.q4;
        else         *(uint4*)(E_f   + (size_t)vrow*DD + (n-768)) = u.q4;
    }
    // ---- phase 2b: leaf h0/c0 per (row, 8-d chunk) ----
    for (int it = 0; it < 2; it++){
        int idx = it*512 + t;            // 0..1023
        int row = idx >> 5, c = idx & 31;
        int d = c*8;
        u16 hv[8], cv[8];
        #pragma unroll
        for (int j = 0; j < 8; j++){
            float iv = bits2f(es[row*ESTR + d + j])       + biou_f[d+j];
            float ov = bits2f(es[row*ESTR + 256 + d + j]) + biou_f[256+d+j];
            float uv = bits2f(es[row*ESTR + 512 + d + j]) + biou_f[512+d+j];
            float cc = sigm(iv)*tanh_(uv);
            float hh = sigm(ov)*tanh_(cc);
            cv[j] = f2bits(cc);
            hv[j] = f2bits(hh);
            hs[row*PAD + d + j] = hv[j];
        }
        union { u16 a[8]; uint4 q4; } uc, uh;
        #pragma unroll
        for (int j = 0; j < 8; j++){ uc.a[j] = cv[j]; uh.a[j] = hv[j]; }
        *(uint4*)(C0 + (size_t)(r0+row)*DD + d) = uc.q4;
        *(uint4*)(H0 + (size_t)(r0+row)*DD + d) = uh.q4;
    }
    __syncthreads();

    // ---- phase 3: HU0 = h0 @ Uf^T (k_lvl GEMM-C proven pattern) ----
    const int d0 = w*32;
    f4 hacc[2][2];
    #pragma unroll
    for (int nt = 0; nt < 2; nt++){ hacc[nt][0] = (f4){0,0,0,0}; hacc[nt][1] = (f4){0,0,0,0}; }
    const u16* Bf0 = Ufm + (size_t)(d0 + ln)*DD;
    const u16* Bf1 = Ufm + (size_t)(d0 + 16 + ln)*DD;
    #pragma unroll 2
    for (int ks = 0; ks < 8; ks++){
        int ko = ks*32 + q*8;
        s8 a0 = ldsA(&hs[ln*PAD + ko]);
        s8 a1 = ldsA(&hs[(16+ln)*PAD + ko]);
        s8 b0 = ldB16(Bf0 + ko);
        s8 b1 = ldB16(Bf1 + ko);
        MFMA(hacc[0][0], a0, b0); MFMA(hacc[0][1], a1, b0);
        MFMA(hacc[1][0], a0, b1); MFMA(hacc[1][1], a1, b1);
    }
    #pragma unroll
    for (int nc = 0; nc < 2; nc++){
        int d = d0 + nc*16 + ln;
        #pragma unroll
        for (int ms = 0; ms < 2; ms++)
          #pragma unroll
          for (int r = 0; r < 4; r++){
            int vrow = r0 + ms*16 + q*4 + r;
            HU0[(size_t)vrow*DD + d] = f2bits(hacc[nc][ms][r]);
        }
    }
}

// ---------------- k_edge0: assemble lvl-1 inputs from vocab tables ----------------
// hsum[p] = H0[v1]+H0[v2] ; fcsum[p] = sig(E_f[fp]+bf+HU0[v1])*C0[v1] + (v2 term)
__global__ __launch_bounds__(512, 4)
void k_edge0(const int* __restrict__ f0, const int* __restrict__ f1, const int* __restrict__ f2,
             const u16* __restrict__ E_f, const u16* __restrict__ H0,
             const u16* __restrict__ C0,  const u16* __restrict__ HU0,
             const float* __restrict__ bf_f,
             u16* __restrict__ hsum_out, u16* __restrict__ fcsum_out)
{
    int gid = blockIdx.x*512 + threadIdx.x;     // 0 .. 24576*32-1
    int row = gid >> 5, ch = gid & 31, d = ch*8;
    int run = row >> 13, rem = row & 8191, b = rem >> 6, jj = rem & 63;
    const int* fp = (run==0) ? f0 : ((run==1) ? f1 : f2);
    int fo = fp[b*TT + 128 + jj];         // own (lvl-1 node) feat
    int v1 = fp[b*TT + 2*jj];             // child j = 2jj   ("even" sibling)
    int v2 = fp[b*TT + 2*jj + 1];         // child j = 2jj+1
    s8 ef  = ldB16(E_f + (size_t)fo*DD + d);
    s8 hu1 = ldB16(HU0 + (size_t)v1*DD + d);
    s8 hu2 = ldB16(HU0 + (size_t)v2*DD + d);
    s8 c1  = ldB16(C0  + (size_t)v1*DD + d);
    s8 c2  = ldB16(C0  + (size_t)v2*DD + d);
    s8 h1  = ldB16(H0  + (size_t)v1*DD + d);
    s8 h2  = ldB16(H0  + (size_t)v2*DD + d);
    union { u16 a[8]; uint4 q4; } uh, uf;
    #pragma unroll
    for (int j = 0; j < 8; j++){
        float e  = bits2f((u16)ef[j]) + bf_f[d+j];
        float fa = sigm(e + bits2f((u16)hu1[j]));
        float fb = sigm(e + bits2f((u16)hu2[j]));
        float fc = fa*bits2f((u16)c1[j]) + fb*bits2f((u16)c2[j]);
        float hsv = bits2f((u16)h1[j]) + bits2f((u16)h2[j]);
        uf.a[j] = f2bits(fc);
        uh.a[j] = f2bits(hsv);
    }
    *(uint4*)(hsum_out  + (size_t)row*DD + d) = uh.q4;
    *(uint4*)(fcsum_out + (size_t)row*DD + d) = uf.q4;
}

// ---------------- per-level kernel (round-6 proven, UNCHANGED; lvl >= 1) ----------------
__global__ __launch_bounds__(512, 4)
void k_lvl(int lvl, int cLog,
           const int* __restrict__ f0, const int* __restrict__ f1, const int* __restrict__ f2,
           const u16* __restrict__ E_iou, const u16* __restrict__ E_f,
           const u16* __restrict__ Uiou, const u16* __restrict__ Ufm,
           const float* __restrict__ biou_f, const float* __restrict__ bf_f,
           const u16* __restrict__ hsum_in, const u16* __restrict__ fcsum_in,
           u16* __restrict__ hsum_out, u16* __restrict__ fcsum_out,
           u16* __restrict__ hroot)
{
    __shared__ u16 hs[32*PAD];
    const int t = threadIdx.x, w = t>>6, lane = t&63, ln = lane&15, q = lane>>4;
    const int cnt = 1 << cLog, S = 256 - 2*cnt;
    const int r0 = blockIdx.x*32, d0 = w*32;
    const bool haveU = (lvl > 0);
    const bool haveP = (lvl < 7);

    int feat[2][4], featp[2][2];
    #pragma unroll
    for (int ms = 0; ms < 2; ms++)
      #pragma unroll
      for (int r = 0; r < 4; r++){
        int rho = r0 + ms*16 + q*4 + r;
        int run = rho >> (7+cLog);
        int rem = rho & ((1<<(7+cLog)) - 1);
        int b = rem >> cLog, jj = rem & (cnt-1);
        const int* fp = (run==0) ? f0 : ((run==1) ? f1 : f2);
        feat[ms][r] = fp[b*TT + S + jj];
        if (haveP && (r&1)==0)
            featp[ms][r>>1] = fp[b*TT + (256-cnt) + (jj>>1)];
      }

    f4 acc[6][2];
    #pragma unroll
    for (int nt = 0; nt < 6; nt++){ acc[nt][0] = (f4){0,0,0,0}; acc[nt][1] = (f4){0,0,0,0}; }
    if (haveU){
        const u16* a0p = hsum_in + (size_t)(r0+ln)*DD;
        const u16* a1p = hsum_in + (size_t)(r0+16+ln)*DD;
        const u16* Bp[6];
        #pragma unroll
        for (int nt = 0; nt < 6; nt++){
            int n = (nt>>1)*256 + d0 + (nt&1)*16 + ln;
            Bp[nt] = Uiou + (size_t)n*DD;
        }
        #pragma unroll 2
        for (int ks = 0; ks < 8; ks++){
            int ko = ks*32 + q*8;
            s8 a0 = ldB16(a0p + ko);
            s8 a1 = ldB16(a1p + ko);
            #pragma unroll
            for (int nt = 0; nt < 6; nt++){
                s8 bb = ldB16(Bp[nt] + ko);
                MFMA(acc[nt][0], a0, bb);
                MFMA(acc[nt][1], a1, bb);
            }
        }
    }

    float cv[2][2][4];
    #pragma unroll
    for (int nc = 0; nc < 2; nc++){
        int d = d0 + nc*16 + ln;
        float bi = biou_f[d], bo = biou_f[256+d], bu = biou_f[512+d];
        #pragma unroll
        for (int ms = 0; ms < 2; ms++){
            float hv[4];
            #pragma unroll
            for (int r = 0; r < 4; r++){
                int rho = r0 + ms*16 + q*4 + r;
                size_t eb = (size_t)feat[ms][r]*768 + d;
                float iv = acc[0+nc][ms][r] + bits2f(E_iou[eb])       + bi;
                float ov = acc[2+nc][ms][r] + bits2f(E_iou[eb + 256]) + bo;
                float uv = acc[4+nc][ms][r] + bits2f(E_iou[eb + 512]) + bu;
                float cs = haveU ? bits2f(fcsum_in[(size_t)rho*DD + d]) : 0.f;
                float c = sigm(iv)*tanh_(uv) + cs;
                float h = sigm(ov)*tanh_(c);
                cv[nc][ms][r] = c;
                hv[r] = h;
                if (haveP) hs[(ms*16 + q*4 + r)*PAD + d] = f2bits(h);
                else       hroot[(size_t)rho*DD + d] = f2bits(h);
            }
            if (haveP){
                int prow = (r0>>1) + ms*8 + q*2;
                hsum_out[(size_t)prow*DD + d]     = f2bits(hv[0] + hv[1]);
                hsum_out[(size_t)(prow+1)*DD + d] = f2bits(hv[2] + hv[3]);
            }
        }
    }

    if (haveP){
        __syncthreads();
        f4 hacc[2][2];
        #pragma unroll
        for (int nt = 0; nt < 2; nt++){ hacc[nt][0] = (f4){0,0,0,0}; hacc[nt][1] = (f4){0,0,0,0}; }
        const u16* Bf0 = Ufm + (size_t)(d0 + ln)*DD;
        const u16* Bf1 = Ufm + (size_t)(d0 + 16 + ln)*DD;
        #pragma unroll 2
        for (int ks = 0; ks < 8; ks++){
            int ko = ks*32 + q*8;
            s8 a0 = ldsA(&hs[ln*PAD + ko]);
            s8 a1 = ldsA(&hs[(16+ln)*PAD + ko]);
            s8 b0 = ldB16(Bf0 + ko);
            s8 b1 = ldB16(Bf1 + ko);
            MFMA(hacc[0][0], a0, b0); MFMA(hacc[0][1], a1, b0);
            MFMA(hacc[1][0], a0, b1); MFMA(hacc[1][1], a1, b1);
        }
        #pragma unroll
        for (int nc = 0; nc < 2; nc++){
            int d = d0 + nc*16 + ln;
            float bfv = bf_f[d];
            #pragma unroll
            for (int ms = 0; ms < 2; ms++){
                float fs0, fs1;
                #pragma unroll
                for (int r = 0; r < 4; r++){
                    float ef = bits2f(E_f[(size_t)featp[ms][r>>1]*DD + d]);
                    float fc = sigm(ef + bfv + hacc[nc][ms][r]) * cv[nc][ms][r];
                    if (r == 0) fs0 = fc;
                    else if (r == 1) fs0 += fc;
                    else if (r == 2) fs1 = fc;
                    else fs1 += fc;
                }
                int prow = (r0>>1) + ms*8 + q*2;
                fcsum_out[(size_t)prow*DD + d]     = f2bits(fs0);
                fcsum_out[(size_t)(prow+1)*DD + d] = f2bits(fs1);
            }
        }
    }
}

// ---------------- final: bilinear combine + MLP (proven epilogue) ----------------
__global__ __launch_bounds__(256)
void k_final(const u16* __restrict__ hroot,
             const float* __restrict__ fc1w, const float* __restrict__ fc1b,
             const float* __restrict__ fc2w, const float* __restrict__ fc2b,
             void* __restrict__ out, const int* __restrict__ flag)
{
    int b = blockIdx.x, t = threadIdx.x;
    __shared__ float sprod[DD];
    __shared__ float shb[DD];
    __shared__ float shid[128];
    float hc  = bits2f(hroot[(0*NTREE + b)*DD + t]);
    float ha  = bits2f(hroot[(1*NTREE + b)*DD + t]);
    float hbv = bits2f(hroot[(2*NTREE + b)*DD + t]);
    sprod[t] = hc * ha;
    shb[t]   = hbv;
    __syncthreads();
    for (int s = 128; s > 0; s >>= 1){
        if (t < s) sprod[t] += sprod[t + s];
        __syncthreads();
    }
    float dot = sprod[0];
    if (t < 128){
        float acc = fc1b[t];
        for (int k = 0; k < DD; k++)
            acc = fmaf(dot * shb[k], fc1w[t*DD + k], acc);
        shid[t] = fmaxf(acc, 0.f);
    }
    __syncthreads();
    if (t < 3){
        float acc = fc2b[t];
        for (int j = 0; j < 128; j++)
            acc = fmaf(fc2w[t*128 + j], shid[j], acc);
        float v = fmaxf(acc, 0.f);
        if (flag[0]) ((bf16*)out)[b*3 + t] = __float2bfloat16(v);
        else         ((float*)out)[b*3 + t] = v;
    }
}

extern "C" void kernel_launch(void* const* d_in, const int* in_sizes, int n_in,
                              void* d_out, int out_size, void* d_ws, size_t ws_size,
                              hipStream_t stream)
{
    const int* f0 = (const int*)d_in[0];
    const int* f1 = (const int*)d_in[1];
    const int* f2 = (const int*)d_in[2];
    // d_in[3..7] static forest metadata — unused (structure compile-time known)
    const void* emb  = d_in[8];
    const void* Wiou = d_in[9];
    const void* biou = d_in[10];
    const void* Uiou = d_in[11];
    const void* Wf   = d_in[12];
    const void* bfv  = d_in[13];
    const void* Uf   = d_in[14];
    const void* fc1w = d_in[15];
    const void* fc1b = d_in[16];
    const void* fc2w = d_in[17];
    const void* fc2b = d_in[18];

    char* base = (char*)d_ws;
    size_t off = 0;
    auto take = [&](size_t bytes) -> char* {
        char* p = base + off;
        off = (off + bytes + 255) & ~(size_t)255;
        return p;
    };
    int*   flag   = (int*)  take(256);
    u16*   embb   = (u16*)  take((size_t)L_EMBP*2);
    u16*   wioub  = (u16*)  take((size_t)L_WIOU*2);
    u16*   uioub  = (u16*)  take((size_t)L_UIOU*2);
    u16*   wfb    = (u16*)  take((size_t)L_WF*2);
    u16*   ufb    = (u16*)  take((size_t)L_UF*2);
    float* biou_f = (float*)take(S_BIOU*4);
    float* bf_f   = (float*)take(S_BF*4);
    float* fc1w_f = (float*)take(S_F1W*4);
    float* fc1b_f = (float*)take(S_F1B*4);
    float* fc2w_f = (float*)take(S_F2W*4);
    float* fc2b_f = (float*)take(S_F2B*4);
    u16*   E_iou  = (u16*)  take((size_t)VPAD*768*2);      // 15.4 MB
    u16*   E_f    = (u16*)  take((size_t)VPAD*DD*2);       // 5.13 MB
    u16*   H0     = (u16*)  take((size_t)VPAD*DD*2);       // 5.13 MB
    u16*   C0     = (u16*)  take((size_t)VPAD*DD*2);       // 5.13 MB
    u16*   HU0    = (u16*)  take((size_t)VPAD*DD*2);       // 5.13 MB
    u16*   HA     = (u16*)  take((size_t)24576*DD*2);      // hsum, even-lvl slot (12.6 MB)
    u16*   HB     = (u16*)  take((size_t)12288*DD*2);      // hsum, odd-lvl slot
    u16*   FA     = (u16*)  take((size_t)24576*DD*2);      // fcsum, even-lvl slot
    u16*   FB     = (u16*)  take((size_t)12288*DD*2);      // fcsum, odd-lvl slot
    u16*   hroot  = (u16*)  take((size_t)NRUNS*NTREE*DD*2);
    // total ~80 MB (< proven 119 MB)

    k_detect<<<1, 256, 0, stream>>>((const u16*)emb, flag);
    k_cvtb<<<2048, 256, 0, stream>>>(emb, Wiou, Uiou, Wf, Uf,
                                     embb, wioub, uioub, wfb, ufb, flag);
    k_small<<<135, 256, 0, stream>>>(biou, bfv, fc1w, fc1b, fc2w, fc2b,
                                     biou_f, bf_f, fc1w_f, fc1b_f, fc2w_f, fc2b_f, flag);
    k_vocab2<<<VPAD/32, 512, 0, stream>>>(embb, wioub, wfb, ufb, biou_f,
                                          E_iou, E_f, H0, C0, HU0);
    // level-0 dispatch replaced by table-driven edge assembly (writes lvl-1 inputs -> HA/FA)
    k_edge0<<<24576*32/512, 512, 0, stream>>>(f0, f1, f2, E_f, H0, C0, HU0, bf_f, HA, FA);

    for (int lvl = 1; lvl <= 7; lvl++){
        int cLog = 7 - lvl;
        int rows = NRUNS*NTREE*(128 >> lvl);
        int blocks = rows / 32;
        int pe = lvl & 1;
        u16* hs_o = pe ? HB : HA;
        u16* fc_o = pe ? FB : FA;
        const u16* hs_i = pe ? HA : HB;      // lvl1 reads HA/FA (written by k_edge0)
        const u16* fc_i = pe ? FA : FB;
        k_lvl<<<blocks, 512, 0, stream>>>(lvl, cLog, f0, f1, f2,
                                          E_iou, E_f, uioub, ufb,
                                          biou_f, bf_f,
                                          hs_i, fc_i, hs_o, fc_o, hroot);
    }
    k_final<<<NTREE, 256, 0, stream>>>(hroot, fc1w_f, fc1b_f, fc2w_f, fc2b_f, d_out, flag);
}

// Round 8
// 438.868 us; speedup vs baseline: 1.6033x; 1.0603x over previous
//
#include <hip/hip_runtime.h>
#include <hip/hip_bf16.h>

typedef __hip_bfloat16 bf16;
typedef unsigned short u16;
typedef __attribute__((ext_vector_type(8))) short s8;   // 8 bf16 = one MFMA A/B fragment
typedef __attribute__((ext_vector_type(4))) float f4;   // MFMA C/D fragment

#define NRUNS 3
#define NTREE 128
#define TT    255
#define DD    256
#define VPAD  10016    /* vocab padded to 32 */
#define PAD   258      /* LDS row stride in u16 for 256-wide rows */
#define ESTR  776      /* LDS row stride in u16 for 768-wide E rows (2-way conflicts only) */

__device__ __forceinline__ float bits2f(u16 b){ union{unsigned u; float f;} x; x.u = ((unsigned)b)<<16; return x.f; }
__device__ __forceinline__ u16   f2bits(float f){ bf16 h = __float2bfloat16(f); return *(u16*)&h; }
__device__ __forceinline__ float sigm(float x){ return 1.f/(1.f+__expf(-x)); }
__device__ __forceinline__ float tanh_(float x){ return 1.f - 2.f/(__expf(2.f*x)+1.f); }

// ---------------- dtype autodetect (proven) ----------------
__global__ void k_detect(const u16* __restrict__ raw, int* __restrict__ flag){
    int t = threadIdx.x;
    int hit = 0;
    if (t < 128){
        u16 w = raw[2*t];
        int e = (w >> 7) & 0xFF;
        hit = (e >= 100 && e <= 141) ? 1 : 0;
    }
    __shared__ int cnt;
    if (t == 0) cnt = 0;
    __syncthreads();
    atomicAdd(&cnt, hit);
    __syncthreads();
    if (t == 0) flag[0] = (cnt >= 64) ? 1 : 0;
}

__device__ __forceinline__ u16 cvt1b(const void* p, int i, int isb){
    return isb ? ((const u16*)p)[i] : f2bits(((const float*)p)[i]);
}
__device__ __forceinline__ float cvt1f(const void* p, int i, int isb){
    return isb ? bits2f(((const u16*)p)[i]) : ((const float*)p)[i];
}

// fused any->bf16 conversion: emb (zero-padded to VPAD rows) + 4 weights
#define L_EMB  (10000*256)
#define L_EMBP (VPAD*256)
#define L_WIOU (768*256)
#define L_UIOU (768*256)
#define L_WF   (256*256)
#define L_UF   (256*256)
#define L_ALL  (L_EMBP + L_WIOU + L_UIOU + L_WF + L_UF)
__global__ void k_cvtb(const void* __restrict__ s0, const void* __restrict__ s1,
                       const void* __restrict__ s2, const void* __restrict__ s3,
                       const void* __restrict__ s4,
                       u16* __restrict__ d0, u16* __restrict__ d1, u16* __restrict__ d2,
                       u16* __restrict__ d3, u16* __restrict__ d4,
                       const int* __restrict__ flag){
    int isb = flag[0];
    for (int i = blockIdx.x*blockDim.x + threadIdx.x; i < L_ALL; i += gridDim.x*blockDim.x){
        int j = i;
        if (j < L_EMBP){ d0[j] = (j < L_EMB) ? cvt1b(s0, j, isb) : (u16)0; continue; } j -= L_EMBP;
        if (j < L_WIOU){ d1[j] = cvt1b(s1, j, isb); continue; } j -= L_WIOU;
        if (j < L_UIOU){ d2[j] = cvt1b(s2, j, isb); continue; } j -= L_UIOU;
        if (j < L_WF){ d3[j] = cvt1b(s3, j, isb); continue; } j -= L_WF;
        d4[j] = cvt1b(s4, j, isb);
    }
}

// fused any->f32 conversion of biases + FC weights
#define S_BIOU 768
#define S_BF   256
#define S_F1W  (128*256)
#define S_F1B  128
#define S_F2W  (3*128)
#define S_F2B  3
#define S_ALL  (S_BIOU+S_BF+S_F1W+S_F1B+S_F2W+S_F2B)
__global__ void k_small(const void* __restrict__ s0, const void* __restrict__ s1,
                        const void* __restrict__ s2, const void* __restrict__ s3,
                        const void* __restrict__ s4, const void* __restrict__ s5,
                        float* __restrict__ d0, float* __restrict__ d1, float* __restrict__ d2,
                        float* __restrict__ d3, float* __restrict__ d4, float* __restrict__ d5,
                        const int* __restrict__ flag){
    int isb = flag[0];
    for (int i = blockIdx.x*blockDim.x + threadIdx.x; i < S_ALL; i += gridDim.x*blockDim.x){
        int j = i;
        if (j < S_BIOU){ d0[j] = cvt1f(s0, j, isb); continue; } j -= S_BIOU;
        if (j < S_BF){ d1[j] = cvt1f(s1, j, isb); continue; } j -= S_BF;
        if (j < S_F1W){ d2[j] = cvt1f(s2, j, isb); continue; } j -= S_F1W;
        if (j < S_F1B){ d3[j] = cvt1f(s3, j, isb); continue; } j -= S_F1B;
        if (j < S_F2W){ d4[j] = cvt1f(s4, j, isb); continue; } j -= S_F2W;
        d5[j] = cvt1f(s5, j, isb);
    }
}

__device__ __forceinline__ s8 ldB16(const u16* p){
    union { uint4 q; s8 v; } u;
    u.q = *(const uint4*)p;
    return u.v;
}
__device__ __forceinline__ s8 ldsA(const u16* p){
    union { unsigned w[4]; s8 v; } u;
    u.w[0] = *(const unsigned*)(p);
    u.w[1] = *(const unsigned*)(p+2);
    u.w[2] = *(const unsigned*)(p+4);
    u.w[3] = *(const unsigned*)(p+6);
    return u.v;
}
#define MFMA(acc,a,b) acc = __builtin_amdgcn_mfma_f32_16x16x32_bf16(a, b, acc, 0, 0, 0)

// ---------------- vocab-space precompute (v2: d-slice wave ownership) ----------------
// Wave w owns d-slice [w*32, w*32+32) for ALL of i,o,u,f -> leaf h0/c0 computed
// straight from D-fragments, no wide LDS staging. LDS = hs only (16.5 KB).
__global__ __launch_bounds__(512, 4)
void k_vocab2(const u16* __restrict__ embb,
              const u16* __restrict__ Wiou, const u16* __restrict__ Wfm,
              const u16* __restrict__ Ufm,  const float* __restrict__ biou_f,
              u16* __restrict__ E_iou, u16* __restrict__ E_f,
              u16* __restrict__ H0, u16* __restrict__ C0, u16* __restrict__ HU0)
{
    __shared__ u16 hs[32*PAD];    // h0 for the HU0 GEMM
    const int t = threadIdx.x, w = t>>6, lane = t&63, ln = lane&15, q = lane>>4;
    const int r0 = blockIdx.x*32, d0 = w*32;

    // B pointers: nt = g*2 + nc, n = g*256 + d0 + nc*16 + ln (g=3 -> Wf)
    const u16* Bp[8];
    #pragma unroll
    for (int g = 0; g < 4; g++)
      #pragma unroll
      for (int nc = 0; nc < 2; nc++){
        int nn = d0 + nc*16 + ln;
        Bp[g*2+nc] = (g < 3) ? (Wiou + (size_t)(g*256+nn)*DD) : (Wfm + (size_t)nn*DD);
      }
    const u16* a0p = embb + (size_t)(r0+ln)*DD;
    const u16* a1p = embb + (size_t)(r0+16+ln)*DD;
    f4 acc[8][2];
    #pragma unroll
    for (int nt = 0; nt < 8; nt++){ acc[nt][0] = (f4){0,0,0,0}; acc[nt][1] = (f4){0,0,0,0}; }
    #pragma unroll 2
    for (int ks = 0; ks < 8; ks++){
        int ko = ks*32 + q*8;
        s8 a0 = ldB16(a0p + ko);
        s8 a1 = ldB16(a1p + ko);
        #pragma unroll
        for (int nt = 0; nt < 8; nt++){
            s8 bb = ldB16(Bp[nt] + ko);
            MFMA(acc[nt][0], a0, bb);
            MFMA(acc[nt][1], a1, bb);
        }
    }
    // epilogue: write E tables + leaf h0/c0 from fragments
    #pragma unroll
    for (int nc = 0; nc < 2; nc++){
        int d = d0 + nc*16 + ln;
        float bi = biou_f[d], bo = biou_f[256+d], bu = biou_f[512+d];
        #pragma unroll
        for (int ms = 0; ms < 2; ms++)
          #pragma unroll
          for (int r = 0; r < 4; r++){
            int vrow = r0 + ms*16 + q*4 + r;
            float ei = acc[0*2+nc][ms][r];
            float eo = acc[1*2+nc][ms][r];
            float eu = acc[2*2+nc][ms][r];
            float ef = acc[3*2+nc][ms][r];
            size_t eb = (size_t)vrow*768 + d;
            E_iou[eb]       = f2bits(ei);
            E_iou[eb + 256] = f2bits(eo);
            E_iou[eb + 512] = f2bits(eu);
            E_f[(size_t)vrow*DD + d] = f2bits(ef);
            float cc = sigm(ei + bi)*tanh_(eu + bu);
            float hh = sigm(eo + bo)*tanh_(cc);
            C0[(size_t)vrow*DD + d] = f2bits(cc);
            H0[(size_t)vrow*DD + d] = f2bits(hh);
            hs[(ms*16 + q*4 + r)*PAD + d] = f2bits(hh);
        }
    }
    __syncthreads();

    // HU0 = h0 @ Uf^T (proven GEMM-C pattern)
    f4 hacc[2][2];
    #pragma unroll
    for (int nt = 0; nt < 2; nt++){ hacc[nt][0] = (f4){0,0,0,0}; hacc[nt][1] = (f4){0,0,0,0}; }
    const u16* Bf0 = Ufm + (size_t)(d0 + ln)*DD;
    const u16* Bf1 = Ufm + (size_t)(d0 + 16 + ln)*DD;
    #pragma unroll 2
    for (int ks = 0; ks < 8; ks++){
        int ko = ks*32 + q*8;
        s8 a0 = ldsA(&hs[ln*PAD + ko]);
        s8 a1 = ldsA(&hs[(16+ln)*PAD + ko]);
        s8 b0 = ldB16(Bf0 + ko);
        s8 b1 = ldB16(Bf1 + ko);
        MFMA(hacc[0][0], a0, b0); MFMA(hacc[0][1], a1, b0);
        MFMA(hacc[1][0], a0, b1); MFMA(hacc[1][1], a1, b1);
    }
    #pragma unroll
    for (int nc = 0; nc < 2; nc++){
        int d = d0 + nc*16 + ln;
        #pragma unroll
        for (int ms = 0; ms < 2; ms++)
          #pragma unroll
          for (int r = 0; r < 4; r++){
            int vrow = r0 + ms*16 + q*4 + r;
            HU0[(size_t)vrow*DD + d] = f2bits(hacc[nc][ms][r]);
        }
    }
}

// ---------------- k_edge0: assemble lvl-1 inputs from vocab tables (proven) ----------------
__global__ __launch_bounds__(512, 4)
void k_edge0(const int* __restrict__ f0, const int* __restrict__ f1, const int* __restrict__ f2,
             const u16* __restrict__ E_f, const u16* __restrict__ H0,
             const u16* __restrict__ C0,  const u16* __restrict__ HU0,
             const float* __restrict__ bf_f,
             u16* __restrict__ hsum_out, u16* __restrict__ fcsum_out)
{
    int gid = blockIdx.x*512 + threadIdx.x;
    int row = gid >> 5, ch = gid & 31, d = ch*8;
    int run = row >> 13, rem = row & 8191, b = rem >> 6, jj = rem & 63;
    const int* fp = (run==0) ? f0 : ((run==1) ? f1 : f2);
    int fo = fp[b*TT + 128 + jj];
    int v1 = fp[b*TT + 2*jj];
    int v2 = fp[b*TT + 2*jj + 1];
    s8 ef  = ldB16(E_f + (size_t)fo*DD + d);
    s8 hu1 = ldB16(HU0 + (size_t)v1*DD + d);
    s8 hu2 = ldB16(HU0 + (size_t)v2*DD + d);
    s8 c1  = ldB16(C0  + (size_t)v1*DD + d);
    s8 c2  = ldB16(C0  + (size_t)v2*DD + d);
    s8 h1  = ldB16(H0  + (size_t)v1*DD + d);
    s8 h2  = ldB16(H0  + (size_t)v2*DD + d);
    union { u16 a[8]; uint4 q4; } uh, uf;
    #pragma unroll
    for (int j = 0; j < 8; j++){
        float e  = bits2f((u16)ef[j]) + bf_f[d+j];
        float fa = sigm(e + bits2f((u16)hu1[j]));
        float fb = sigm(e + bits2f((u16)hu2[j]));
        float fc = fa*bits2f((u16)c1[j]) + fb*bits2f((u16)c2[j]);
        float hsv = bits2f((u16)h1[j]) + bits2f((u16)h2[j]);
        uf.a[j] = f2bits(fc);
        uh.a[j] = f2bits(hsv);
    }
    *(uint4*)(hsum_out  + (size_t)row*DD + d) = uh.q4;
    *(uint4*)(fcsum_out + (size_t)row*DD + d) = uf.q4;
}

// ---------------- per-level kernel (v2: coalesced E_iou row staging) ----------------
__global__ __launch_bounds__(512, 4)
void k_lvl(int lvl, int cLog,
           const int* __restrict__ f0, const int* __restrict__ f1, const int* __restrict__ f2,
           const u16* __restrict__ E_iou, const u16* __restrict__ E_f,
           const u16* __restrict__ Uiou, const u16* __restrict__ Ufm,
           const float* __restrict__ biou_f, const float* __restrict__ bf_f,
           const u16* __restrict__ hsum_in, const u16* __restrict__ fcsum_in,
           u16* __restrict__ hsum_out, u16* __restrict__ fcsum_out,
           u16* __restrict__ hroot)
{
    __shared__ u16 es[32*ESTR];  // 48.5 KB: staged E_iou rows for this block's 32 nodes
    __shared__ u16 hs[32*PAD];   // 16.5 KB: h transpose for GEMM-C
    const int t = threadIdx.x, w = t>>6, lane = t&63, ln = lane&15, q = lane>>4;
    const int cnt = 1 << cLog, S = 256 - 2*cnt;
    const int r0 = blockIdx.x*32, d0 = w*32;
    const bool haveP = (lvl < 7);

    // ---- issue coalesced E_iou row staging loads FIRST (latency hides under GEMM-U) ----
    // thread layout: srow = t>>4 (0..31), c16 = t&15; row = 96 x 16B chunks, 6 per thread.
    uint4 stg[6];
    {
        int srow = t >> 4, c16 = t & 15;
        int rho = r0 + srow;
        int run = rho >> (7+cLog);
        int rem = rho & ((1<<(7+cLog)) - 1);
        int b = rem >> cLog, jj = rem & (cnt-1);
        const int* fp = (run==0) ? f0 : ((run==1) ? f1 : f2);
        int feat_s = fp[b*TT + S + jj];
        const u16* ep = E_iou + (size_t)feat_s*768;
        #pragma unroll
        for (int it = 0; it < 6; it++){
            int chk = it*16 + c16;
            stg[it] = *(const uint4*)(ep + chk*8);
        }
    }

    // parent feats for GEMM-C epilogue
    int featp[2][2];
    if (haveP){
        #pragma unroll
        for (int ms = 0; ms < 2; ms++)
          #pragma unroll
          for (int rr = 0; rr < 2; rr++){
            int rho = r0 + ms*16 + q*4 + rr*2;
            int run = rho >> (7+cLog);
            int rem = rho & ((1<<(7+cLog)) - 1);
            int b = rem >> cLog, jj = rem & (cnt-1);
            const int* fp = (run==0) ? f0 : ((run==1) ? f1 : f2);
            featp[ms][rr] = fp[b*TT + (256-cnt) + (jj>>1)];
          }
    }

    // ---- GEMM-U: hsum_in @ Uiou^T ----
    f4 acc[6][2];
    #pragma unroll
    for (int nt = 0; nt < 6; nt++){ acc[nt][0] = (f4){0,0,0,0}; acc[nt][1] = (f4){0,0,0,0}; }
    {
        const u16* a0p = hsum_in + (size_t)(r0+ln)*DD;
        const u16* a1p = hsum_in + (size_t)(r0+16+ln)*DD;
        const u16* Bp[6];
        #pragma unroll
        for (int nt = 0; nt < 6; nt++){
            int n = (nt>>1)*256 + d0 + (nt&1)*16 + ln;
            Bp[nt] = Uiou + (size_t)n*DD;
        }
        #pragma unroll 2
        for (int ks = 0; ks < 8; ks++){
            int ko = ks*32 + q*8;
            s8 a0 = ldB16(a0p + ko);
            s8 a1 = ldB16(a1p + ko);
            #pragma unroll
            for (int nt = 0; nt < 6; nt++){
                s8 bb = ldB16(Bp[nt] + ko);
                MFMA(acc[nt][0], a0, bb);
                MFMA(acc[nt][1], a1, bb);
            }
        }
    }

    // ---- land staged E rows in LDS ----
    {
        int srow = t >> 4, c16 = t & 15;
        #pragma unroll
        for (int it = 0; it < 6; it++){
            int chk = it*16 + c16;
            *(uint4*)&es[srow*ESTR + chk*8] = stg[it];
        }
    }
    __syncthreads();

    // ---- epilogue: cell update from LDS-staged E; hsum pair-reduce in registers ----
    float cv[2][2][4];
    #pragma unroll
    for (int nc = 0; nc < 2; nc++){
        int d = d0 + nc*16 + ln;
        float bi = biou_f[d], bo = biou_f[256+d], bu = biou_f[512+d];
        #pragma unroll
        for (int ms = 0; ms < 2; ms++){
            float hv[4];
            #pragma unroll
            for (int r = 0; r < 4; r++){
                int m   = ms*16 + q*4 + r;
                int rho = r0 + m;
                float iv = acc[0+nc][ms][r] + bits2f(es[m*ESTR + d])       + bi;
                float ov = acc[2+nc][ms][r] + bits2f(es[m*ESTR + 256 + d]) + bo;
                float uv = acc[4+nc][ms][r] + bits2f(es[m*ESTR + 512 + d]) + bu;
                float cs = bits2f(fcsum_in[(size_t)rho*DD + d]);
                float c = sigm(iv)*tanh_(uv) + cs;
                float h = sigm(ov)*tanh_(c);
                cv[nc][ms][r] = c;
                hv[r] = h;
                if (haveP) hs[m*PAD + d] = f2bits(h);
                else       hroot[(size_t)rho*DD + d] = f2bits(h);
            }
            if (haveP){
                int prow = (r0>>1) + ms*8 + q*2;
                hsum_out[(size_t)prow*DD + d]     = f2bits(hv[0] + hv[1]);
                hsum_out[(size_t)(prow+1)*DD + d] = f2bits(hv[2] + hv[3]);
            }
        }
    }

    // ---- GEMM-C: hU = h@Uf^T, fc = sig(E_f[parent]+bf+hU)*c, pair-reduce ----
    if (haveP){
        __syncthreads();
        f4 hacc[2][2];
        #pragma unroll
        for (int nt = 0; nt < 2; nt++){ hacc[nt][0] = (f4){0,0,0,0}; hacc[nt][1] = (f4){0,0,0,0}; }
        const u16* Bf0 = Ufm + (size_t)(d0 + ln)*DD;
        const u16* Bf1 = Ufm + (size_t)(d0 + 16 + ln)*DD;
        #pragma unroll 2
        for (int ks = 0; ks < 8; ks++){
            int ko = ks*32 + q*8;
            s8 a0 = ldsA(&hs[ln*PAD + ko]);
            s8 a1 = ldsA(&hs[(16+ln)*PAD + ko]);
            s8 b0 = ldB16(Bf0 + ko);
            s8 b1 = ldB16(Bf1 + ko);
            MFMA(hacc[0][0], a0, b0); MFMA(hacc[0][1], a1, b0);
            MFMA(hacc[1][0], a0, b1); MFMA(hacc[1][1], a1, b1);
        }
        #pragma unroll
        for (int nc = 0; nc < 2; nc++){
            int d = d0 + nc*16 + ln;
            float bfv = bf_f[d];
            #pragma unroll
            for (int ms = 0; ms < 2; ms++){
                float fs0, fs1;
                #pragma unroll
                for (int r = 0; r < 4; r++){
                    float ef = bits2f(E_f[(size_t)featp[ms][r>>1]*DD + d]);
                    float fc = sigm(ef + bfv + hacc[nc][ms][r]) * cv[nc][ms][r];
                    if (r == 0) fs0 = fc;
                    else if (r == 1) fs0 += fc;
                    else if (r == 2) fs1 = fc;
                    else fs1 += fc;
                }
                int prow = (r0>>1) + ms*8 + q*2;
                fcsum_out[(size_t)prow*DD + d]     = f2bits(fs0);
                fcsum_out[(size_t)(prow+1)*DD + d] = f2bits(fs1);
            }
        }
    }
}

// ---------------- final: bilinear combine + MLP (proven epilogue) ----------------
__global__ __launch_bounds__(256)
void k_final(const u16* __restrict__ hroot,
             const float* __restrict__ fc1w, const float* __restrict__ fc1b,
             const float* __restrict__ fc2w, const float* __restrict__ fc2b,
             void* __restrict__ out, const int* __restrict__ flag)
{
    int b = blockIdx.x, t = threadIdx.x;
    __shared__ float sprod[DD];
    __shared__ float shb[DD];
    __shared__ float shid[128];
    float hc  = bits2f(hroot[(0*NTREE + b)*DD + t]);
    float ha  = bits2f(hroot[(1*NTREE + b)*DD + t]);
    float hbv = bits2f(hroot[(2*NTREE + b)*DD + t]);
    sprod[t] = hc * ha;
    shb[t]   = hbv;
    __syncthreads();
    for (int s = 128; s > 0; s >>= 1){
        if (t < s) sprod[t] += sprod[t + s];
        __syncthreads();
    }
    float dot = sprod[0];
    if (t < 128){
        float acc = fc1b[t];
        for (int k = 0; k < DD; k++)
            acc = fmaf(dot * shb[k], fc1w[t*DD + k], acc);
        shid[t] = fmaxf(acc, 0.f);
    }
    __syncthreads();
    if (t < 3){
        float acc = fc2b[t];
        for (int j = 0; j < 128; j++)
            acc = fmaf(fc2w[t*128 + j], shid[j], acc);
        float v = fmaxf(acc, 0.f);
        if (flag[0]) ((bf16*)out)[b*3 + t] = __float2bfloat16(v);
        else         ((float*)out)[b*3 + t] = v;
    }
}

extern "C" void kernel_launch(void* const* d_in, const int* in_sizes, int n_in,
                              void* d_out, int out_size, void* d_ws, size_t ws_size,
                              hipStream_t stream)
{
    const int* f0 = (const int*)d_in[0];
    const int* f1 = (const int*)d_in[1];
    const int* f2 = (const int*)d_in[2];
    // d_in[3..7] static forest metadata — unused (structure compile-time known)
    const void* emb  = d_in[8];
    const void* Wiou = d_in[9];
    const void* biou = d_in[10];
    const void* Uiou = d_in[11];
    const void* Wf   = d_in[12];
    const void* bfv  = d_in[13];
    const void* Uf   = d_in[14];
    const void* fc1w = d_in[15];
    const void* fc1b = d_in[16];
    const void* fc2w = d_in[17];
    const void* fc2b = d_in[18];

    char* base = (char*)d_ws;
    size_t off = 0;
    auto take = [&](size_t bytes) -> char* {
        char* p = base + off;
        off = (off + bytes + 255) & ~(size_t)255;
        return p;
    };
    int*   flag   = (int*)  take(256);
    u16*   embb   = (u16*)  take((size_t)L_EMBP*2);
    u16*   wioub  = (u16*)  take((size_t)L_WIOU*2);
    u16*   uioub  = (u16*)  take((size_t)L_UIOU*2);
    u16*   wfb    = (u16*)  take((size_t)L_WF*2);
    u16*   ufb    = (u16*)  take((size_t)L_UF*2);
    float* biou_f = (float*)take(S_BIOU*4);
    float* bf_f   = (float*)take(S_BF*4);
    float* fc1w_f = (float*)take(S_F1W*4);
    float* fc1b_f = (float*)take(S_F1B*4);
    float* fc2w_f = (float*)take(S_F2W*4);
    float* fc2b_f = (float*)take(S_F2B*4);
    u16*   E_iou  = (u16*)  take((size_t)VPAD*768*2);      // 15.4 MB
    u16*   E_f    = (u16*)  take((size_t)VPAD*DD*2);       // 5.13 MB
    u16*   H0     = (u16*)  take((size_t)VPAD*DD*2);
    u16*   C0     = (u16*)  take((size_t)VPAD*DD*2);
    u16*   HU0    = (u16*)  take((size_t)VPAD*DD*2);
    u16*   HA     = (u16*)  take((size_t)24576*DD*2);
    u16*   HB     = (u16*)  take((size_t)12288*DD*2);
    u16*   FA     = (u16*)  take((size_t)24576*DD*2);
    u16*   FB     = (u16*)  take((size_t)12288*DD*2);
    u16*   hroot  = (u16*)  take((size_t)NRUNS*NTREE*DD*2);
    // total ~80 MB (< proven 119 MB)

    k_detect<<<1, 256, 0, stream>>>((const u16*)emb, flag);
    k_cvtb<<<2048, 256, 0, stream>>>(emb, Wiou, Uiou, Wf, Uf,
                                     embb, wioub, uioub, wfb, ufb, flag);
    k_small<<<135, 256, 0, stream>>>(biou, bfv, fc1w, fc1b, fc2w, fc2b,
                                     biou_f, bf_f, fc1w_f, fc1b_f, fc2w_f, fc2b_f, flag);
    k_vocab2<<<VPAD/32, 512, 0, stream>>>(embb, wioub, wfb, ufb, biou_f,
                                          E_iou, E_f, H0, C0, HU0);
    k_edge0<<<24576*32/512, 512, 0, stream>>>(f0, f1, f2, E_f, H0, C0, HU0, bf_f, HA, FA);

    for (int lvl = 1; lvl <= 7; lvl++){
        int cLog = 7 - lvl;
        int rows = NRUNS*NTREE*(128 >> lvl);
        int blocks = rows / 32;
        int pe = lvl & 1;
        u16* hs_o = pe ? HB : HA;
        u16* fc_o = pe ? FB : FA;
        const u16* hs_i = pe ? HA : HB;
        const u16* fc_i = pe ? FA : FB;
        k_lvl<<<blocks, 512, 0, stream>>>(lvl, cLog, f0, f1, f2,
                                          E_iou, E_f, uioub, ufb,
                                          biou_f, bf_f,
                                          hs_i, fc_i, hs_o, fc_o, hroot);
    }
    k_final<<<NTREE, 256, 0, stream>>>(hroot, fc1w_f, fc1b_f, fc2w_f, fc2b_f, d_out, flag);
}